// Round 3
// baseline (935.526 us; speedup 1.0000x reference)
//
#include <hip/hip_runtime.h>

// ---------- types ----------
typedef __bf16 bf16x8 __attribute__((ext_vector_type(8)));
typedef float f32x4 __attribute__((ext_vector_type(4)));
typedef unsigned short u16x8 __attribute__((ext_vector_type(8)));
typedef unsigned short u16x4 __attribute__((ext_vector_type(4)));

__device__ __forceinline__ float b2f_u(unsigned short s) {
  unsigned int u = ((unsigned int)s) << 16;
  float f;
  __builtin_memcpy(&f, &u, 4);
  return f;
}
__device__ __forceinline__ unsigned short f2b_u(float f) {
  unsigned int u;
  __builtin_memcpy(&u, &f, 4);
  unsigned int r = 0x7FFFu + ((u >> 16) & 1u);  // round-to-nearest-even
  return (unsigned short)((u + r) >> 16);
}
__device__ __forceinline__ float silu_f(float x) { return x / (1.f + expf(-x)); }

// ---------- projection GEMM: Y[m,n] = sum_k X[m,k]*W[n,k] + b[n]  (fp32 in) ----------
// MODE 0: Q: rope+silu -> Ct transposed [b][ch][seq] (bf16)
// MODE 1: V: silu -> Ct transposed; rope+silu -> Cn natural [m][ch] (bf16)
template <int MODE>
__global__ __launch_bounds__(256) void proj_gemm(
    const float* __restrict__ A, const float* __restrict__ B,
    unsigned short* __restrict__ Ct, const float* __restrict__ bias,
    unsigned short* __restrict__ Cn) {
  __shared__ __align__(16) unsigned short smem[18432];  // 36864 B
  unsigned short(*sA)[72] = (unsigned short(*)[72])smem;           // 128x72
  unsigned short(*sB)[72] = (unsigned short(*)[72])(smem + 9216);  // 128x72
  unsigned short* sT = smem;                                       // 128x136 epilogue

  const int m0 = blockIdx.y * 128, n0 = blockIdx.x * 128;
  const int tid = threadIdx.x;
  const int lane = tid & 63, wave = tid >> 6;
  const int wm = (wave & 1) << 6, wn = (wave >> 1) << 6;  // 2x2 waves, 64x64 each
  const int l16 = lane & 15, q8 = (lane >> 4) << 3;

  f32x4 acc[4][4] = {};

  for (int kt = 0; kt < 512; kt += 64) {
    f32x4 ra[8], rb[8];
#pragma unroll
    for (int i = 0; i < 8; ++i) {
      int c = tid + (i << 8);              // 0..2047 covers 128x64 f32 tile
      int row = c >> 4, col = (c & 15) << 2;
      ra[i] = *(const f32x4*)(A + (long)(m0 + row) * 512 + kt + col);
      rb[i] = *(const f32x4*)(B + (long)(n0 + row) * 512 + kt + col);
    }
    __syncthreads();
#pragma unroll
    for (int i = 0; i < 8; ++i) {
      int c = tid + (i << 8);
      int row = c >> 4, col = (c & 15) << 2;
      u16x4 a4, b4;
#pragma unroll
      for (int j = 0; j < 4; ++j) {
        a4[j] = f2b_u(ra[i][j]);
        b4[j] = f2b_u(rb[i][j]);
      }
      *(u16x4*)&sA[row][col] = a4;
      *(u16x4*)&sB[row][col] = b4;
    }
    __syncthreads();
#pragma unroll
    for (int kk = 0; kk < 2; ++kk) {
      bf16x8 af[4], bfv[4];
#pragma unroll
      for (int i = 0; i < 4; ++i) {
        af[i] = *(const bf16x8*)&sA[wm + (i << 4) + l16][(kk << 5) + q8];
        bfv[i] = *(const bf16x8*)&sB[wn + (i << 4) + l16][(kk << 5) + q8];
      }
#pragma unroll
      for (int i = 0; i < 4; ++i)
#pragma unroll
        for (int j = 0; j < 4; ++j)
          acc[i][j] = __builtin_amdgcn_mfma_f32_16x16x32_bf16(af[i], bfv[j], acc[i][j], 0, 0, 0);
    }
  }

  const int rq = (lane >> 4) << 2;  // C frag: row = wm+i*16+rq+r, col = wn+j*16+l16
#pragma unroll
  for (int j = 0; j < 4; ++j) {
    float bv = bias[n0 + wn + (j << 4) + l16];
#pragma unroll
    for (int i = 0; i < 4; ++i)
#pragma unroll
      for (int r = 0; r < 4; ++r) acc[i][j][r] += bv;
  }
  const bool ropecol = (n0 == 0) && (wn == 0);  // ch 0..63 live in waves 0/1, frags j=0..3
  const int bq_ = m0 >> 13;   // batch
  const int s0_ = m0 & 8191;  // seq base in batch

  auto rope_inplace = [&]() {
#pragma unroll
    for (int j = 0; j < 4; ++j) {
      int gch = (j << 4) + l16;  // 0..63
      float invf = 1.f / powf(10000.f, (float)(gch >> 1) * (1.f / 32.f));
      float sgn = (gch & 1) ? 1.f : -1.f;
#pragma unroll
      for (int i = 0; i < 4; ++i)
#pragma unroll
        for (int r = 0; r < 4; ++r) {
          float pos = (float)(s0_ + wm + (i << 4) + rq + r);
          float sn, cs;
          sincosf(pos * invf, &sn, &cs);
          float v = acc[i][j][r];
          float p = __shfl_xor(v, 1);  // partner channel (bit0 of lane == bit0 of ch)
          acc[i][j][r] = v * cs + sgn * sn * p;
        }
    }
  };

  if (MODE == 0) {
    if (ropecol) rope_inplace();
    __syncthreads();
#pragma unroll
    for (int i = 0; i < 4; ++i)
#pragma unroll
      for (int j = 0; j < 4; ++j)
#pragma unroll
        for (int r = 0; r < 4; ++r)
          sT[(wn + (j << 4) + l16) * 136 + wm + (i << 4) + rq + r] = f2b_u(silu_f(acc[i][j][r]));
    __syncthreads();
#pragma unroll
    for (int it = 0; it < 8; ++it) {
      int c = tid + (it << 8);
      int rr = c >> 4, c8 = (c & 15) << 3;
      u16x8 v = *(const u16x8*)&sT[rr * 136 + c8];
      *(u16x8*)(Ct + ((long)(bq_ * 512 + n0 + rr)) * 8192 + s0_ + c8) = v;
    }
  } else {
    // pass 1: VT = silu(Y) transposed
    __syncthreads();
#pragma unroll
    for (int i = 0; i < 4; ++i)
#pragma unroll
      for (int j = 0; j < 4; ++j)
#pragma unroll
        for (int r = 0; r < 4; ++r)
          sT[(wn + (j << 4) + l16) * 136 + wm + (i << 4) + rq + r] = f2b_u(silu_f(acc[i][j][r]));
    __syncthreads();
#pragma unroll
    for (int it = 0; it < 8; ++it) {
      int c = tid + (it << 8);
      int rr = c >> 4, c8 = (c & 15) << 3;
      u16x8 v = *(const u16x8*)&sT[rr * 136 + c8];
      *(u16x8*)(Ct + ((long)(bq_ * 512 + n0 + rr)) * 8192 + s0_ + c8) = v;
    }
    // pass 2: Kn = silu(rope(Y)) natural
    if (ropecol) rope_inplace();
    __syncthreads();
#pragma unroll
    for (int i = 0; i < 4; ++i)
#pragma unroll
      for (int j = 0; j < 4; ++j)
#pragma unroll
        for (int r = 0; r < 4; ++r)
          sT[(wm + (i << 4) + rq + r) * 136 + wn + (j << 4) + l16] = f2b_u(silu_f(acc[i][j][r]));
    __syncthreads();
#pragma unroll
    for (int it = 0; it < 8; ++it) {
      int c = tid + (it << 8);
      int rr = c >> 4, c8 = (c & 15) << 3;
      u16x8 v = *(const u16x8*)&sT[rr * 136 + c8];
      *(u16x8*)(Cn + ((long)(m0 + rr)) * 512 + n0 + c8) = v;
    }
  }
}

// ---------- bf16 NT GEMM: C[m,n] = sum_k A[m,k]*B[n,k], fp32 out ----------
// OMODE 2: fp32 atomicAdd (split-K)   OMODE 3: fp32 store
template <int OMODE>
__global__ __launch_bounds__(256) void gemm_bf(
    const unsigned short* __restrict__ A, const unsigned short* __restrict__ B,
    float* __restrict__ Cp, int lda, int ldb, int ldc, int K,
    long aBatch, long bBatch, long cBatch, int ksplit) {
  __shared__ __align__(16) unsigned short smem[18432];
  unsigned short(*sA)[72] = (unsigned short(*)[72])smem;
  unsigned short(*sB)[72] = (unsigned short(*)[72])(smem + 9216);

  const int bz = blockIdx.z;
  const int batch = bz / ksplit;
  const int kc = bz - batch * ksplit;
  const unsigned short* A0 = A + batch * aBatch + (long)kc * K;
  const unsigned short* B0 = B + batch * bBatch + (long)kc * K;
  const int m0 = blockIdx.y * 128, n0 = blockIdx.x * 128;
  const int tid = threadIdx.x;
  const int lane = tid & 63, wave = tid >> 6;
  const int wm = (wave & 1) << 6, wn = (wave >> 1) << 6;
  const int l16 = lane & 15, q8 = (lane >> 4) << 3;

  f32x4 acc[4][4] = {};

  for (int kt = 0; kt < K; kt += 64) {
    u16x8 ra[4], rb[4];
#pragma unroll
    for (int i = 0; i < 4; ++i) {
      int c = tid + (i << 8);
      int row = c >> 3, col = (c & 7) << 3;
      ra[i] = *(const u16x8*)(A0 + (long)(m0 + row) * lda + kt + col);
      rb[i] = *(const u16x8*)(B0 + (long)(n0 + row) * ldb + kt + col);
    }
    __syncthreads();
#pragma unroll
    for (int i = 0; i < 4; ++i) {
      int c = tid + (i << 8);
      int row = c >> 3, col = (c & 7) << 3;
      *(u16x8*)&sA[row][col] = ra[i];
      *(u16x8*)&sB[row][col] = rb[i];
    }
    __syncthreads();
#pragma unroll
    for (int kk = 0; kk < 2; ++kk) {
      bf16x8 af[4], bfv[4];
#pragma unroll
      for (int i = 0; i < 4; ++i) {
        af[i] = *(const bf16x8*)&sA[wm + (i << 4) + l16][(kk << 5) + q8];
        bfv[i] = *(const bf16x8*)&sB[wn + (i << 4) + l16][(kk << 5) + q8];
      }
#pragma unroll
      for (int i = 0; i < 4; ++i)
#pragma unroll
        for (int j = 0; j < 4; ++j)
          acc[i][j] = __builtin_amdgcn_mfma_f32_16x16x32_bf16(af[i], bfv[j], acc[i][j], 0, 0, 0);
    }
  }

  const int rq = (lane >> 4) << 2;
#pragma unroll
  for (int i = 0; i < 4; ++i)
#pragma unroll
    for (int j = 0; j < 4; ++j)
#pragma unroll
      for (int r = 0; r < 4; ++r) {
        int gm = m0 + wm + (i << 4) + rq + r;
        int gn = n0 + wn + (j << 4) + l16;
        if (OMODE == 2)
          atomicAdd(Cp + batch * cBatch + (long)gm * ldc + gn, acc[i][j][r]);
        else
          Cp[batch * cBatch + (long)gm * ldc + gn] = acc[i][j][r];
      }
}

// ---------- per-(batch,d) column mean of C2f[b][e][d] over e ----------
__global__ __launch_bounds__(64) void colmean(const float* __restrict__ C, float* __restrict__ Cd) {
  const int bd = blockIdx.x;  // b*512+d
  const int b = bd >> 9, d = bd & 511;
  const float* p = C + ((long)b << 18) + d;
  float s = 0.f;
  for (int e = threadIdx.x; e < 512; e += 64) s += p[(long)e << 9];
  s += __shfl_xor(s, 1);
  s += __shfl_xor(s, 2);
  s += __shfl_xor(s, 4);
  s += __shfl_xor(s, 8);
  s += __shfl_xor(s, 16);
  s += __shfl_xor(s, 32);
  if (threadIdx.x == 0) Cd[bd] = s * (1.f / 512.f);
}

// ---------- centered fp32 -> bf16:  out = bf16(C2f[b][e][d] - Cd[b][d]) ----------
// (subtracted term is e-independent -> cancels exactly in GroupNorm mean)
__global__ __launch_bounds__(256) void cvt_center(const float* __restrict__ in,
                                                  const float* __restrict__ Cd,
                                                  unsigned short* __restrict__ out) {
  int i = (blockIdx.x * 256 + threadIdx.x) * 4;
  f32x4 x = *(const f32x4*)(in + i);
  int b = i >> 18, d = i & 511;
  f32x4 c = *(const f32x4*)(Cd + (b << 9) + d);
  u16x4 o;
#pragma unroll
  for (int j = 0; j < 4; ++j) o[j] = f2b_u(x[j] - c[j]);
  *(u16x4*)(out + i) = o;
}

// ---------- GroupNorm (8 groups x 64 ch), two-pass, fp32 in/out ----------
__global__ __launch_bounds__(256) void gn_kernel(
    const float* __restrict__ Pre, const float* __restrict__ gnw, const float* __restrict__ gnb,
    const float* __restrict__ Sh, const float* __restrict__ Sc, float* __restrict__ out) {
  const int row = blockIdx.x * 4 + (threadIdx.x >> 6);
  const int lane = threadIdx.x & 63;
  const float* rp = Pre + (long)row * 512 + lane * 8;
  f32x4 a = *(const f32x4*)rp;
  f32x4 b4 = *(const f32x4*)(rp + 4);
  float xs[8];
#pragma unroll
  for (int j = 0; j < 4; ++j) {
    xs[j] = a[j];
    xs[4 + j] = b4[j];
  }
  float s = 0.f;
#pragma unroll
  for (int j = 0; j < 8; ++j) s += xs[j];
  s += __shfl_xor(s, 1);
  s += __shfl_xor(s, 2);
  s += __shfl_xor(s, 4);  // 8 lanes x 8 ch = one 64-ch group
  float mean = s * (1.f / 64.f);
  float sq = 0.f;
#pragma unroll
  for (int j = 0; j < 8; ++j) {
    float d = xs[j] - mean;
    sq += d * d;
  }
  sq += __shfl_xor(sq, 1);
  sq += __shfl_xor(sq, 2);
  sq += __shfl_xor(sq, 4);
  float inv = rsqrtf(sq * (1.f / 64.f) + 1e-6f);
  f32x4 w1 = *(const f32x4*)(gnw + lane * 8);
  f32x4 w2 = *(const f32x4*)(gnw + lane * 8 + 4);
  f32x4 g1 = *(const f32x4*)(gnb + lane * 8);
  f32x4 g2 = *(const f32x4*)(gnb + lane * 8 + 4);
  f32x4 o1, o2;
#pragma unroll
  for (int j = 0; j < 4; ++j) {
    o1[j] = (xs[j] - mean) * inv * w1[j] + g1[j];
    o2[j] = (xs[4 + j] - mean) * inv * w2[j] + g2[j];
  }
  *(f32x4*)(out + (long)row * 512 + lane * 8) = o1;
  *(f32x4*)(out + (long)row * 512 + lane * 8 + 4) = o2;
  if (blockIdx.x == 0 && threadIdx.x == 0) {
    out[16777216] = Sh[0];  // S_h passthrough
    out[16777217] = Sc[0];  // S_C passthrough
  }
}

// ---------- launch ----------
extern "C" void kernel_launch(void* const* d_in, const int* in_sizes, int n_in,
                              void* d_out, int out_size, void* d_ws, size_t ws_size,
                              hipStream_t stream) {
  const float* Xq = (const float*)d_in[0];
  const float* Xkv = (const float*)d_in[1];
  const float* Sh = (const float*)d_in[2];
  const float* Sc = (const float*)d_in[3];
  const float* Wq = (const float*)d_in[4];
  const float* bq = (const float*)d_in[5];
  // d_in[6]=Wk, d_in[7]=bk : dead code in reference
  const float* Wv = (const float*)d_in[8];
  const float* bv = (const float*)d_in[9];
  const float* gnw = (const float*)d_in[10];
  const float* gnb = (const float*)d_in[11];

  char* ws = (char*)d_ws;
  // layout (bytes), peak = 106,962,944:
  unsigned short* QT = (unsigned short*)(ws);                // [4][512][8192] bf16 = 33,554,432
  unsigned short* VT = (unsigned short*)(ws + 33554432L);    // 33,554,432
  unsigned short* Kn = (unsigned short*)(ws + 67108864L);    // [4][8192][512] bf16 = 33,554,432
  float* C2f = (float*)(ws + 100663296L);                    // [4][512][512] f32 = 4,194,304
  unsigned short* C2c = (unsigned short*)(ws + 104857600L);  // centered bf16 = 2,097,152
  float* Cd = (float*)(ws + 106954752L);                     // [4][512] f32 = 8,192
  float* Pre = (float*)ws;  // [4][8192][512] f32 overlays QT+VT (dead after QtV)
  float* outp = (float*)d_out;

  if (ws_size < 106962944UL) return;

  // 1+2: fused projections (M=32768, N=512, K=512)
  dim3 g1(4, 256, 1);
  proj_gemm<0><<<g1, 256, 0, stream>>>(Xq, Wq, QT, bq, nullptr);
  proj_gemm<1><<<g1, 256, 0, stream>>>(Xkv, Wv, VT, bv, Kn);

  // 3: QtV^T[e,d] = sum_n V'[n,e] Q'[n,d]  (M=N=512, K=8192, split-K=16)
  (void)hipMemsetAsync(C2f, 0, 4194304, stream);
  gemm_bf<2><<<dim3(4, 4, 64), 256, 0, stream>>>(VT, QT, C2f, 8192, 8192, 512, 512, 4194304L,
                                                 4194304L, 262144L, 16);
  // 3b: center per (b,d) and round to bf16
  colmean<<<2048, 64, 0, stream>>>(C2f, Cd);
  cvt_center<<<1024, 256, 0, stream>>>(C2f, Cd, C2c);

  // 4: Pre[n,e] = sum_d K'[n,d] * (QtV[d,e] - Cd[d])
  gemm_bf<3><<<dim3(4, 64, 4), 256, 0, stream>>>(Kn, C2c, Pre, 512, 512, 512, 512, 4194304L,
                                                 262144L, 4194304L, 1);

  // 5: GroupNorm + scalar passthrough
  gn_kernel<<<8192, 256, 0, stream>>>(Pre, gnw, gnb, Sh, Sc, outp);
}

// Round 4
// 782.037 us; speedup vs baseline: 1.1963x; 1.1963x over previous
//
#include <hip/hip_runtime.h>

// ---------- types ----------
typedef __bf16 bf16x8 __attribute__((ext_vector_type(8)));
typedef float f32x4 __attribute__((ext_vector_type(4)));
typedef unsigned short u16x8 __attribute__((ext_vector_type(8)));
typedef unsigned short u16x4 __attribute__((ext_vector_type(4)));

__device__ __forceinline__ unsigned short f2b_u(float f) {
  unsigned int u;
  __builtin_memcpy(&u, &f, 4);
  unsigned int r = 0x7FFFu + ((u >> 16) & 1u);  // round-to-nearest-even
  return (unsigned short)((u + r) >> 16);
}
__device__ __forceinline__ float silu_f(float x) { return x / (1.f + expf(-x)); }

// ---------- fp32 -> bf16 (weights) ----------
__global__ __launch_bounds__(256) void cvt_w(const float* __restrict__ in,
                                             unsigned short* __restrict__ out) {
  int i = (blockIdx.x * 256 + threadIdx.x) * 4;  // grid 256 -> 262144 f32
  f32x4 x = *(const f32x4*)(in + i);
  u16x4 o;
#pragma unroll
  for (int j = 0; j < 4; ++j) o[j] = f2b_u(x[j]);
  *(u16x4*)(out + i) = o;
}

// ---------- projection GEMM: Y[m,n] = sum_k X[m,k]*Wb[n,k] + b[n] ----------
// A fp32 (converted to bf16 while staging, low reg pressure), B bf16 pre-converted.
// MODE 0: Q: rope+silu -> Ct transposed [b][ch][seq]
// MODE 1: V: silu -> Ct transposed; rope+silu -> Cn natural
// 1-D grid 1024: m_tile = blk & 255 (same-A sharers 256 apart -> same XCD), n_tile = blk >> 8
template <int MODE>
__global__ __launch_bounds__(256) void proj_gemm(
    const float* __restrict__ A, const unsigned short* __restrict__ B,
    unsigned short* __restrict__ Ct, const float* __restrict__ bias,
    unsigned short* __restrict__ Cn) {
  __shared__ __align__(16) unsigned short smem[18432];  // 36864 B
  unsigned short(*sA)[72] = (unsigned short(*)[72])smem;           // 128x72
  unsigned short(*sB)[72] = (unsigned short(*)[72])(smem + 9216);  // 128x72
  unsigned short* sT = smem;                                       // 128x136 epilogue

  const int blk = blockIdx.x;
  const int m0 = (blk & 255) << 7, n0 = (blk >> 8) << 7;
  const int tid = threadIdx.x;
  const int lane = tid & 63, wave = tid >> 6;
  const int wm = (wave & 1) << 6, wn = (wave >> 1) << 6;  // 2x2 waves, 64x64 each
  const int l16 = lane & 15, q8 = (lane >> 4) << 3;

  f32x4 acc[4][4] = {};

  for (int kt = 0; kt < 512; kt += 64) {
    u16x4 ca[8];  // A tile 128x64 f32 -> bf16: 8 B/thread-chunk x 8
    u16x8 rb[4];  // B tile 128x64 bf16: 16 B/thread-chunk x 4
#pragma unroll
    for (int i = 0; i < 8; ++i) {
      int c = tid + (i << 8);
      int row = c >> 4, col = (c & 15) << 2;
      f32x4 t = *(const f32x4*)(A + (long)(m0 + row) * 512 + kt + col);
#pragma unroll
      for (int j = 0; j < 4; ++j) ca[i][j] = f2b_u(t[j]);
    }
#pragma unroll
    for (int i = 0; i < 4; ++i) {
      int c = tid + (i << 8);
      int row = c >> 3, col = (c & 7) << 3;
      rb[i] = *(const u16x8*)(B + (long)(n0 + row) * 512 + kt + col);
    }
    __syncthreads();
#pragma unroll
    for (int i = 0; i < 8; ++i) {
      int c = tid + (i << 8);
      *(u16x4*)&sA[c >> 4][(c & 15) << 2] = ca[i];
    }
#pragma unroll
    for (int i = 0; i < 4; ++i) {
      int c = tid + (i << 8);
      *(u16x8*)&sB[c >> 3][(c & 7) << 3] = rb[i];
    }
    __syncthreads();
#pragma unroll
    for (int kk = 0; kk < 2; ++kk) {
      bf16x8 af[4], bfv[4];
#pragma unroll
      for (int i = 0; i < 4; ++i) {
        af[i] = *(const bf16x8*)&sA[wm + (i << 4) + l16][(kk << 5) + q8];
        bfv[i] = *(const bf16x8*)&sB[wn + (i << 4) + l16][(kk << 5) + q8];
      }
#pragma unroll
      for (int i = 0; i < 4; ++i)
#pragma unroll
        for (int j = 0; j < 4; ++j)
          acc[i][j] = __builtin_amdgcn_mfma_f32_16x16x32_bf16(af[i], bfv[j], acc[i][j], 0, 0, 0);
    }
  }

  const int rq = (lane >> 4) << 2;  // C frag: row = wm+i*16+rq+r, col = wn+j*16+l16
#pragma unroll
  for (int j = 0; j < 4; ++j) {
    float bv = bias[n0 + wn + (j << 4) + l16];
#pragma unroll
    for (int i = 0; i < 4; ++i)
#pragma unroll
      for (int r = 0; r < 4; ++r) acc[i][j][r] += bv;
  }
  const bool ropecol = (n0 == 0) && (wn == 0);  // ch 0..63
  const int bq_ = m0 >> 13;   // batch
  const int s0_ = m0 & 8191;  // seq base in batch

  auto rope_inplace = [&]() {
#pragma unroll
    for (int j = 0; j < 4; ++j) {
      int gch = (j << 4) + l16;  // 0..63
      float invf = 1.f / powf(10000.f, (float)(gch >> 1) * (1.f / 32.f));
      float sgn = (gch & 1) ? 1.f : -1.f;
#pragma unroll
      for (int i = 0; i < 4; ++i)
#pragma unroll
        for (int r = 0; r < 4; ++r) {
          float pos = (float)(s0_ + wm + (i << 4) + rq + r);
          float sn, cs;
          sincosf(pos * invf, &sn, &cs);
          float v = acc[i][j][r];
          float p = __shfl_xor(v, 1);  // partner channel
          acc[i][j][r] = v * cs + sgn * sn * p;
        }
    }
  };

  if (MODE == 0) {
    if (ropecol) rope_inplace();
    __syncthreads();
#pragma unroll
    for (int i = 0; i < 4; ++i)
#pragma unroll
      for (int j = 0; j < 4; ++j)
#pragma unroll
        for (int r = 0; r < 4; ++r)
          sT[(wn + (j << 4) + l16) * 136 + wm + (i << 4) + rq + r] = f2b_u(silu_f(acc[i][j][r]));
    __syncthreads();
#pragma unroll
    for (int it = 0; it < 8; ++it) {
      int c = tid + (it << 8);
      int rr = c >> 4, c8 = (c & 15) << 3;
      u16x8 v = *(const u16x8*)&sT[rr * 136 + c8];
      *(u16x8*)(Ct + ((long)(bq_ * 512 + n0 + rr)) * 8192 + s0_ + c8) = v;
    }
  } else {
    // pass 1: VT = silu(Y) transposed
    __syncthreads();
#pragma unroll
    for (int i = 0; i < 4; ++i)
#pragma unroll
      for (int j = 0; j < 4; ++j)
#pragma unroll
        for (int r = 0; r < 4; ++r)
          sT[(wn + (j << 4) + l16) * 136 + wm + (i << 4) + rq + r] = f2b_u(silu_f(acc[i][j][r]));
    __syncthreads();
#pragma unroll
    for (int it = 0; it < 8; ++it) {
      int c = tid + (it << 8);
      int rr = c >> 4, c8 = (c & 15) << 3;
      u16x8 v = *(const u16x8*)&sT[rr * 136 + c8];
      *(u16x8*)(Ct + ((long)(bq_ * 512 + n0 + rr)) * 8192 + s0_ + c8) = v;
    }
    // pass 2: Kn = silu(rope(Y)) natural
    if (ropecol) rope_inplace();
    __syncthreads();
#pragma unroll
    for (int i = 0; i < 4; ++i)
#pragma unroll
      for (int j = 0; j < 4; ++j)
#pragma unroll
        for (int r = 0; r < 4; ++r)
          sT[(wm + (i << 4) + rq + r) * 136 + wn + (j << 4) + l16] = f2b_u(silu_f(acc[i][j][r]));
    __syncthreads();
#pragma unroll
    for (int it = 0; it < 8; ++it) {
      int c = tid + (it << 8);
      int rr = c >> 4, c8 = (c & 15) << 3;
      u16x8 v = *(const u16x8*)&sT[rr * 136 + c8];
      *(u16x8*)(Cn + ((long)(m0 + rr)) * 512 + n0 + c8) = v;
    }
  }
}

// ---------- QtV: C2f[b][e][d] += sum_n V'[n,e] Q'[n,d]  (split-K=8, atomics) ----------
// 1-D grid 512, XCD-swizzled: low3 = m_hi + 2*n_hi + 4*z_lo
__global__ __launch_bounds__(256) void gemm_qtv(
    const unsigned short* __restrict__ A, const unsigned short* __restrict__ B,
    float* __restrict__ Cp) {
  __shared__ __align__(16) unsigned short smem[18432];
  unsigned short(*sA)[72] = (unsigned short(*)[72])smem;
  unsigned short(*sB)[72] = (unsigned short(*)[72])(smem + 9216);

  const int blk = blockIdx.x;
  const int low3 = blk & 7, hi = blk >> 3;
  const int m = ((low3 & 1) << 1) | (hi & 1);
  const int n = (low3 & 2) | ((hi >> 1) & 1);
  const int z = ((hi >> 2) << 1) | (low3 >> 2);  // 0..31
  const int batch = z >> 3, kc = z & 7;          // K-chunk 1024
  const unsigned short* A0 = A + (long)batch * 4194304 + (long)kc * 1024;
  const unsigned short* B0 = B + (long)batch * 4194304 + (long)kc * 1024;
  const int m0 = m << 7, n0 = n << 7;
  const int tid = threadIdx.x;
  const int lane = tid & 63, wave = tid >> 6;
  const int wm = (wave & 1) << 6, wn = (wave >> 1) << 6;
  const int l16 = lane & 15, q8 = (lane >> 4) << 3;

  f32x4 acc[4][4] = {};

  for (int kt = 0; kt < 1024; kt += 64) {
    u16x8 ra[4], rb[4];
#pragma unroll
    for (int i = 0; i < 4; ++i) {
      int c = tid + (i << 8);
      int row = c >> 3, col = (c & 7) << 3;
      ra[i] = *(const u16x8*)(A0 + (long)(m0 + row) * 8192 + kt + col);
      rb[i] = *(const u16x8*)(B0 + (long)(n0 + row) * 8192 + kt + col);
    }
    __syncthreads();
#pragma unroll
    for (int i = 0; i < 4; ++i) {
      int c = tid + (i << 8);
      int row = c >> 3, col = (c & 7) << 3;
      *(u16x8*)&sA[row][col] = ra[i];
      *(u16x8*)&sB[row][col] = rb[i];
    }
    __syncthreads();
#pragma unroll
    for (int kk = 0; kk < 2; ++kk) {
      bf16x8 af[4], bfv[4];
#pragma unroll
      for (int i = 0; i < 4; ++i) {
        af[i] = *(const bf16x8*)&sA[wm + (i << 4) + l16][(kk << 5) + q8];
        bfv[i] = *(const bf16x8*)&sB[wn + (i << 4) + l16][(kk << 5) + q8];
      }
#pragma unroll
      for (int i = 0; i < 4; ++i)
#pragma unroll
        for (int j = 0; j < 4; ++j)
          acc[i][j] = __builtin_amdgcn_mfma_f32_16x16x32_bf16(af[i], bfv[j], acc[i][j], 0, 0, 0);
    }
  }

  const int rq = (lane >> 4) << 2;
#pragma unroll
  for (int i = 0; i < 4; ++i)
#pragma unroll
    for (int j = 0; j < 4; ++j)
#pragma unroll
      for (int r = 0; r < 4; ++r) {
        int gm = m0 + wm + (i << 4) + rq + r;
        int gn = n0 + wn + (j << 4) + l16;
        atomicAdd(Cp + (long)batch * 262144 + (long)gm * 512 + gn, acc[i][j][r]);
      }
}

// ---------- per-(batch,d) column mean of C2f[b][e][d] over e ----------
__global__ __launch_bounds__(64) void colmean(const float* __restrict__ C, float* __restrict__ Cd) {
  const int bd = blockIdx.x;  // b*512+d
  const int b = bd >> 9, d = bd & 511;
  const float* p = C + ((long)b << 18) + d;
  float s = 0.f;
  for (int e = threadIdx.x; e < 512; e += 64) s += p[(long)e << 9];
  s += __shfl_xor(s, 1);
  s += __shfl_xor(s, 2);
  s += __shfl_xor(s, 4);
  s += __shfl_xor(s, 8);
  s += __shfl_xor(s, 16);
  s += __shfl_xor(s, 32);
  if (threadIdx.x == 0) Cd[bd] = s * (1.f / 512.f);
}

// ---------- centered fp32 -> bf16 + scalar passthrough ----------
__global__ __launch_bounds__(256) void cvt_center(const float* __restrict__ in,
                                                  const float* __restrict__ Cd,
                                                  unsigned short* __restrict__ out,
                                                  const float* __restrict__ Sh,
                                                  const float* __restrict__ Sc,
                                                  float* __restrict__ outp) {
  int i = (blockIdx.x * 256 + threadIdx.x) * 4;
  f32x4 x = *(const f32x4*)(in + i);
  int b = i >> 18, d = i & 511;
  f32x4 c = *(const f32x4*)(Cd + (b << 9) + d);
  u16x4 o;
#pragma unroll
  for (int j = 0; j < 4; ++j) o[j] = f2b_u(x[j] - c[j]);
  *(u16x4*)(out + i) = o;
  if (blockIdx.x == 0 && threadIdx.x == 0) {
    outp[16777216] = Sh[0];
    outp[16777217] = Sc[0];
  }
}

// ---------- GEMM4 + fused GroupNorm: out[b][n][e] = GN_e( sum_d K'[n,d]*C2c[e,d] ) ----------
// Each wave's 64-col span = exactly one GN group (64 ch); quad-local shfl_xor row stats.
// 1-D grid 1024: mt = blk & 255 (global m-tile), n = blk >> 8
__global__ __launch_bounds__(256) void gemm4_gn(
    const unsigned short* __restrict__ A, const unsigned short* __restrict__ B,
    const float* __restrict__ gnw, const float* __restrict__ gnb,
    float* __restrict__ out) {
  __shared__ __align__(16) unsigned short smem[18432];
  unsigned short(*sA)[72] = (unsigned short(*)[72])smem;
  unsigned short(*sB)[72] = (unsigned short(*)[72])(smem + 9216);

  const int blk = blockIdx.x;
  const int mt = blk & 255, n = blk >> 8;
  const int batch = mt >> 6;
  const int m0 = (mt & 63) << 7, n0 = n << 7;
  const unsigned short* A0 = A + (long)batch * 4194304;
  const unsigned short* B0 = B + (long)batch * 262144;
  const int tid = threadIdx.x;
  const int lane = tid & 63, wave = tid >> 6;
  const int wm = (wave & 1) << 6, wn = (wave >> 1) << 6;
  const int l16 = lane & 15, q8 = (lane >> 4) << 3;

  f32x4 acc[4][4] = {};

  for (int kt = 0; kt < 512; kt += 64) {
    u16x8 ra[4], rb[4];
#pragma unroll
    for (int i = 0; i < 4; ++i) {
      int c = tid + (i << 8);
      int row = c >> 3, col = (c & 7) << 3;
      ra[i] = *(const u16x8*)(A0 + (long)(m0 + row) * 512 + kt + col);
      rb[i] = *(const u16x8*)(B0 + (long)(n0 + row) * 512 + kt + col);
    }
    __syncthreads();
#pragma unroll
    for (int i = 0; i < 4; ++i) {
      int c = tid + (i << 8);
      int row = c >> 3, col = (c & 7) << 3;
      *(u16x8*)&sA[row][col] = ra[i];
      *(u16x8*)&sB[row][col] = rb[i];
    }
    __syncthreads();
#pragma unroll
    for (int kk = 0; kk < 2; ++kk) {
      bf16x8 af[4], bfv[4];
#pragma unroll
      for (int i = 0; i < 4; ++i) {
        af[i] = *(const bf16x8*)&sA[wm + (i << 4) + l16][(kk << 5) + q8];
        bfv[i] = *(const bf16x8*)&sB[wn + (i << 4) + l16][(kk << 5) + q8];
      }
#pragma unroll
      for (int i = 0; i < 4; ++i)
#pragma unroll
        for (int j = 0; j < 4; ++j)
          acc[i][j] = __builtin_amdgcn_mfma_f32_16x16x32_bf16(af[i], bfv[j], acc[i][j], 0, 0, 0);
    }
  }

  const int rq = (lane >> 4) << 2;
  float wv[4], bb[4];
#pragma unroll
  for (int j = 0; j < 4; ++j) {
    int gn = n0 + wn + (j << 4) + l16;
    wv[j] = gnw[gn];
    bb[j] = gnb[gn];
  }
  float* obase = out + (long)batch * 4194304;
#pragma unroll
  for (int i = 0; i < 4; ++i) {
    // per-row stats over this wave's 64 cols (= one full GN group)
    float mean[4], inv[4];
#pragma unroll
    for (int r = 0; r < 4; ++r) {
      float s = acc[i][0][r] + acc[i][1][r] + acc[i][2][r] + acc[i][3][r];
      s += __shfl_xor(s, 1);
      s += __shfl_xor(s, 2);
      s += __shfl_xor(s, 4);
      s += __shfl_xor(s, 8);  // 16 lanes of the quad share these 4 rows
      mean[r] = s * (1.f / 64.f);
      float sq = 0.f;
#pragma unroll
      for (int j = 0; j < 4; ++j) {
        float d = acc[i][j][r] - mean[r];
        sq += d * d;
      }
      sq += __shfl_xor(sq, 1);
      sq += __shfl_xor(sq, 2);
      sq += __shfl_xor(sq, 4);
      sq += __shfl_xor(sq, 8);
      inv[r] = rsqrtf(sq * (1.f / 64.f) + 1e-6f);
    }
#pragma unroll
    for (int j = 0; j < 4; ++j) {
      int gn = n0 + wn + (j << 4) + l16;
#pragma unroll
      for (int r = 0; r < 4; ++r) {
        int gm = m0 + wm + (i << 4) + rq + r;
        obase[(long)gm * 512 + gn] = (acc[i][j][r] - mean[r]) * inv[r] * wv[j] + bb[j];
      }
    }
  }
}

// ---------- launch ----------
extern "C" void kernel_launch(void* const* d_in, const int* in_sizes, int n_in,
                              void* d_out, int out_size, void* d_ws, size_t ws_size,
                              hipStream_t stream) {
  const float* Xq = (const float*)d_in[0];
  const float* Xkv = (const float*)d_in[1];
  const float* Sh = (const float*)d_in[2];
  const float* Sc = (const float*)d_in[3];
  const float* Wq = (const float*)d_in[4];
  const float* bq = (const float*)d_in[5];
  // d_in[6]=Wk, d_in[7]=bk : dead code in reference
  const float* Wv = (const float*)d_in[8];
  const float* bv = (const float*)d_in[9];
  const float* gnw = (const float*)d_in[10];
  const float* gnb = (const float*)d_in[11];

  char* ws = (char*)d_ws;
  // layout (bytes), peak = 106,962,944 (proven available in round 3):
  unsigned short* QT = (unsigned short*)(ws);                // [4][512][8192] bf16 = 33,554,432
  unsigned short* VT = (unsigned short*)(ws + 33554432L);    // 33,554,432
  unsigned short* Kn = (unsigned short*)(ws + 67108864L);    // [4][8192][512] bf16 = 33,554,432
  float* C2f = (float*)(ws + 100663296L);                    // [4][512][512] f32 = 4,194,304
  unsigned short* C2c = (unsigned short*)(ws + 104857600L);  // centered bf16 = 2,097,152
  float* Cd = (float*)(ws + 106954752L);                     // [4][512] f32 = 8,192
  // W bf16 overlaid on C2f region (dead until the memset below)
  unsigned short* Wqb = (unsigned short*)(ws + 100663296L);            // 524,288
  unsigned short* Wvb = (unsigned short*)(ws + 100663296L + 524288L);  // 524,288
  float* outp = (float*)d_out;

  if (ws_size < 106962944UL) return;

  // 0: weights fp32 -> bf16
  cvt_w<<<256, 256, 0, stream>>>(Wq, Wqb);
  cvt_w<<<256, 256, 0, stream>>>(Wv, Wvb);

  // 1+2: fused projections (M=32768, N=512, K=512), XCD-swizzled 1-D grid
  proj_gemm<0><<<1024, 256, 0, stream>>>(Xq, Wqb, QT, bq, nullptr);
  proj_gemm<1><<<1024, 256, 0, stream>>>(Xkv, Wvb, VT, bv, Kn);

  // 3: QtV^T[e,d] accumulation (split-K=8, fp32 atomics)
  (void)hipMemsetAsync(C2f, 0, 4194304, stream);
  gemm_qtv<<<512, 256, 0, stream>>>(VT, QT, C2f);

  // 3b: center per (b,d) and round to bf16; scalar passthrough
  colmean<<<2048, 64, 0, stream>>>(C2f, Cd);
  cvt_center<<<1024, 256, 0, stream>>>(C2f, Cd, C2c, Sh, Sc, outp);

  // 4: out = GroupNorm( K' @ (QtV - Cd) ) fused
  gemm4_gn<<<1024, 256, 0, stream>>>(Kn, C2c, gnw, gnb, outp);
}

// Round 6
// 403.919 us; speedup vs baseline: 2.3161x; 1.9361x over previous
//
#include <hip/hip_runtime.h>

// ---------- types ----------
typedef __bf16 bf16x8 __attribute__((ext_vector_type(8)));
typedef float f32x4 __attribute__((ext_vector_type(4)));
typedef unsigned short u16x8 __attribute__((ext_vector_type(8)));
typedef unsigned short u16x4 __attribute__((ext_vector_type(4)));

__device__ __forceinline__ unsigned short f2b_u(float f) {
  unsigned int u;
  __builtin_memcpy(&u, &f, 4);
  unsigned int r = 0x7FFFu + ((u >> 16) & 1u);  // round-to-nearest-even
  return (unsigned short)((u + r) >> 16);
}
__device__ __forceinline__ float silu_f(float x) { return x / (1.f + expf(-x)); }

// ---------- fp32 -> bf16 (weights) ----------
__global__ __launch_bounds__(256) void cvt_w(const float* __restrict__ in,
                                             unsigned short* __restrict__ out) {
  int i = (blockIdx.x * 256 + threadIdx.x) * 4;  // grid 256 -> 262144 f32
  f32x4 x = *(const f32x4*)(in + i);
  u16x4 o;
#pragma unroll
  for (int j = 0; j < 4; ++j) o[j] = f2b_u(x[j]);
  *(u16x4*)(out + i) = o;
}

// ---------- rope sin/cos table: TBL[pos][ip] = (sin, cos), pos<8192, ip<32 ----------
__global__ __launch_bounds__(256) void gen_tbl(float* __restrict__ T) {
  int idx = blockIdx.x * 256 + threadIdx.x;  // grid 1024 -> 262144
  int pos = idx >> 5, ip = idx & 31;
  float f = (float)pos * powf(10000.f, -(float)ip * (1.f / 32.f));
  float sn, cs;
  sincosf(f, &sn, &cs);
  T[idx * 2] = sn;
  T[idx * 2 + 1] = cs;
}

// ---------- projection: Y[m,:] = X[m,:] @ W^T + b, full-N blocks (A fetched ONCE) ----------
// grid 256 (m-stripes of 128), block 1024 (16 waves: wm=(w&1)*64, wn=(w>>1)*64)
// MODE 0: rope+silu -> Ct transposed [b][ch][seq]
// MODE 1: silu -> Ct transposed; rope+silu -> Cn natural
template <int MODE>
__global__ __launch_bounds__(1024) void proj2(
    const float* __restrict__ A, const unsigned short* __restrict__ B,
    unsigned short* __restrict__ Ct, const float* __restrict__ bias,
    unsigned short* __restrict__ Cn, const float* __restrict__ TBL) {
  __shared__ __align__(16) unsigned short smem[25600];             // 51200 B
  unsigned short(*sA)[40] = (unsigned short(*)[40])smem;           // 128x40 (K=32 +8 pad)
  unsigned short(*sB)[40] = (unsigned short(*)[40])(smem + 5120);  // 512x40
  unsigned short* sT = smem;  // epilogue: [512][40] (20480 u16) or [32][520] (16640 u16)

  const int m0 = blockIdx.x << 7;
  const int tid = threadIdx.x;
  const int lane = tid & 63, w = tid >> 6;
  const int wm = (w & 1) << 6, wn = (w >> 1) << 6;
  const int l16 = lane & 15, q8 = (lane >> 4) << 3;
  const int ar = tid >> 3, ac = (tid & 7) << 2;  // A stage: 128x32 f32
  const int br = tid >> 1, bc = (tid & 1) << 4;  // B stage: 512x32 bf16

  f32x4 acc[4][4] = {};

  for (int kt = 0; kt < 512; kt += 32) {
    f32x4 av = *(const f32x4*)(A + (long)(m0 + ar) * 512 + kt + ac);
    u16x8 b0 = *(const u16x8*)(B + (long)br * 512 + kt + bc);
    u16x8 b1 = *(const u16x8*)(B + (long)br * 512 + kt + bc + 8);
    u16x4 a4;
#pragma unroll
    for (int j = 0; j < 4; ++j) a4[j] = f2b_u(av[j]);
    __syncthreads();
    *(u16x4*)&sA[ar][ac] = a4;
    *(u16x8*)&sB[br][bc] = b0;
    *(u16x8*)&sB[br][bc + 8] = b1;
    __syncthreads();
    bf16x8 af[4], bf[4];
#pragma unroll
    for (int i = 0; i < 4; ++i) af[i] = *(const bf16x8*)&sA[wm + (i << 4) + l16][q8];
#pragma unroll
    for (int j = 0; j < 4; ++j) bf[j] = *(const bf16x8*)&sB[wn + (j << 4) + l16][q8];
#pragma unroll
    for (int i = 0; i < 4; ++i)
#pragma unroll
      for (int j = 0; j < 4; ++j)
        acc[i][j] = __builtin_amdgcn_mfma_f32_16x16x32_bf16(af[i], bf[j], acc[i][j], 0, 0, 0);
  }

  const int rq = (lane >> 4) << 2;  // frag row base; C: row=wm+i*16+rq+r, col=wn+j*16+l16
#pragma unroll
  for (int j = 0; j < 4; ++j) {
    float bv = bias[wn + (j << 4) + l16];
#pragma unroll
    for (int i = 0; i < 4; ++i)
#pragma unroll
      for (int r = 0; r < 4; ++r) acc[i][j][r] += bv;
  }
  const int bq_ = m0 >> 13;   // batch
  const int s0_ = m0 & 8191;  // seq base  (rope position MUST use this, not m0!)

  // rope (waves with wn==0 hold ch 0..63) — MODE 0 now, MODE 1 after pass 1
  if (MODE == 0 && wn == 0) {
#pragma unroll
    for (int j = 0; j < 4; ++j) {
      int ip = (j << 3) + (l16 >> 1);
      float sgn = (l16 & 1) ? 1.f : -1.f;
#pragma unroll
      for (int i = 0; i < 4; ++i)
#pragma unroll
        for (int r = 0; r < 4; ++r) {
          int pos = s0_ + wm + (i << 4) + rq + r;
          const float* t = TBL + ((long)pos << 6) + (ip << 1);
          float sn = t[0], cs = t[1];
          float v = acc[i][j][r];
          float p = __shfl_xor(v, 1);
          acc[i][j][r] = v * cs + sgn * sn * p;
        }
    }
  }

  // transposed store (QT/VT): 4 phases of 32 seq-cols via sT[512][40]
  unsigned short* dstT = Ct + ((long)bq_ << 22);  // bq*512*8192
#pragma unroll
  for (int p = 0; p < 4; ++p) {
    __syncthreads();
    if ((w & 1) == (p >> 1)) {
      int ib = (p & 1) << 1;
#pragma unroll
      for (int ii = 0; ii < 2; ++ii) {
#pragma unroll
        for (int j = 0; j < 4; ++j)
#pragma unroll
          for (int r = 0; r < 4; ++r)
            sT[(wn + (j << 4) + l16) * 40 + (ii << 4) + rq + r] =
                f2b_u(silu_f(acc[ib + ii][j][r]));
      }
    }
    __syncthreads();
    int row = tid >> 1, cb = (tid & 1) << 4;
    u16x8 v0 = *(const u16x8*)&sT[row * 40 + cb];
    u16x8 v1 = *(const u16x8*)&sT[row * 40 + cb + 8];
    long o = (long)row * 8192 + s0_ + (p << 5) + cb;
    *(u16x8*)(dstT + o) = v0;
    *(u16x8*)(dstT + o + 8) = v1;
  }

  if (MODE == 1) {
    // rope for K'
    if (wn == 0) {
#pragma unroll
      for (int j = 0; j < 4; ++j) {
        int ip = (j << 3) + (l16 >> 1);
        float sgn = (l16 & 1) ? 1.f : -1.f;
#pragma unroll
        for (int i = 0; i < 4; ++i)
#pragma unroll
          for (int r = 0; r < 4; ++r) {
            int pos = s0_ + wm + (i << 4) + rq + r;
            const float* t = TBL + ((long)pos << 6) + (ip << 1);
            float sn = t[0], cs = t[1];
            float v = acc[i][j][r];
            float p = __shfl_xor(v, 1);
            acc[i][j][r] = v * cs + sgn * sn * p;
          }
      }
    }
    // natural store (Kn): 4 phases of 32 seq-rows via sT2[32][520]
#pragma unroll
    for (int p = 0; p < 4; ++p) {
      __syncthreads();
      if ((w & 1) == (p >> 1)) {
        int ib = (p & 1) << 1;
#pragma unroll
        for (int ii = 0; ii < 2; ++ii) {
#pragma unroll
          for (int j = 0; j < 4; ++j)
#pragma unroll
            for (int r = 0; r < 4; ++r)
              sT[((ii << 4) + rq + r) * 520 + wn + (j << 4) + l16] =
                  f2b_u(silu_f(acc[ib + ii][j][r]));
        }
      }
      __syncthreads();
      int row = tid >> 5, cb = (tid & 31) << 4;
      u16x8 v0 = *(const u16x8*)&sT[row * 520 + cb];
      u16x8 v1 = *(const u16x8*)&sT[row * 520 + cb + 8];
      long o = (long)(m0 + (p << 5) + row) * 512 + cb;
      *(u16x8*)(Cn + o) = v0;
      *(u16x8*)(Cn + o + 8) = v1;
    }
  }
}

// ---------- QtV: C2f[b][e][d] += sum_n V'[n,e] Q'[n,d]  (split-K=8, atomics) ----------
__global__ __launch_bounds__(256) void gemm_qtv(
    const unsigned short* __restrict__ A, const unsigned short* __restrict__ B,
    float* __restrict__ Cp) {
  __shared__ __align__(16) unsigned short smem[18432];
  unsigned short(*sA)[72] = (unsigned short(*)[72])smem;
  unsigned short(*sB)[72] = (unsigned short(*)[72])(smem + 9216);

  const int blk = blockIdx.x;
  const int low3 = blk & 7, hi = blk >> 3;
  const int m = ((low3 & 1) << 1) | (hi & 1);
  const int n = (low3 & 2) | ((hi >> 1) & 1);
  const int z = ((hi >> 2) << 1) | (low3 >> 2);  // 0..31
  const int batch = z >> 3, kc = z & 7;          // K-chunk 1024
  const unsigned short* A0 = A + (long)batch * 4194304 + (long)kc * 1024;
  const unsigned short* B0 = B + (long)batch * 4194304 + (long)kc * 1024;
  const int m0 = m << 7, n0 = n << 7;
  const int tid = threadIdx.x;
  const int lane = tid & 63, wave = tid >> 6;
  const int wm = (wave & 1) << 6, wn = (wave >> 1) << 6;
  const int l16 = lane & 15, q8 = (lane >> 4) << 3;

  f32x4 acc[4][4] = {};

  for (int kt = 0; kt < 1024; kt += 64) {
    u16x8 ra[4], rb[4];
#pragma unroll
    for (int i = 0; i < 4; ++i) {
      int c = tid + (i << 8);
      int row = c >> 3, col = (c & 7) << 3;
      ra[i] = *(const u16x8*)(A0 + (long)(m0 + row) * 8192 + kt + col);
      rb[i] = *(const u16x8*)(B0 + (long)(n0 + row) * 8192 + kt + col);
    }
    __syncthreads();
#pragma unroll
    for (int i = 0; i < 4; ++i) {
      int c = tid + (i << 8);
      int row = c >> 3, col = (c & 7) << 3;
      *(u16x8*)&sA[row][col] = ra[i];
      *(u16x8*)&sB[row][col] = rb[i];
    }
    __syncthreads();
#pragma unroll
    for (int kk = 0; kk < 2; ++kk) {
      bf16x8 af[4], bfv[4];
#pragma unroll
      for (int i = 0; i < 4; ++i) {
        af[i] = *(const bf16x8*)&sA[wm + (i << 4) + l16][(kk << 5) + q8];
        bfv[i] = *(const bf16x8*)&sB[wn + (i << 4) + l16][(kk << 5) + q8];
      }
#pragma unroll
      for (int i = 0; i < 4; ++i)
#pragma unroll
        for (int j = 0; j < 4; ++j)
          acc[i][j] = __builtin_amdgcn_mfma_f32_16x16x32_bf16(af[i], bfv[j], acc[i][j], 0, 0, 0);
    }
  }

  const int rq = (lane >> 4) << 2;
#pragma unroll
  for (int i = 0; i < 4; ++i)
#pragma unroll
    for (int j = 0; j < 4; ++j)
#pragma unroll
      for (int r = 0; r < 4; ++r) {
        int gm = m0 + wm + (i << 4) + rq + r;
        int gn = n0 + wn + (j << 4) + l16;
        atomicAdd(Cp + (long)batch * 262144 + (long)gm * 512 + gn, acc[i][j][r]);
      }
}

// ---------- per-(batch,d) column mean of C2f[b][e][d] over e ----------
__global__ __launch_bounds__(64) void colmean(const float* __restrict__ C, float* __restrict__ Cd) {
  const int bd = blockIdx.x;
  const int b = bd >> 9, d = bd & 511;
  const float* p = C + ((long)b << 18) + d;
  float s = 0.f;
  for (int e = threadIdx.x; e < 512; e += 64) s += p[(long)e << 9];
  s += __shfl_xor(s, 1);
  s += __shfl_xor(s, 2);
  s += __shfl_xor(s, 4);
  s += __shfl_xor(s, 8);
  s += __shfl_xor(s, 16);
  s += __shfl_xor(s, 32);
  if (threadIdx.x == 0) Cd[bd] = s * (1.f / 512.f);
}

// ---------- centered fp32 -> bf16 + scalar passthrough ----------
__global__ __launch_bounds__(256) void cvt_center(const float* __restrict__ in,
                                                  const float* __restrict__ Cd,
                                                  unsigned short* __restrict__ out,
                                                  const float* __restrict__ Sh,
                                                  const float* __restrict__ Sc,
                                                  float* __restrict__ outp) {
  int i = (blockIdx.x * 256 + threadIdx.x) * 4;
  f32x4 x = *(const f32x4*)(in + i);
  int b = i >> 18, d = i & 511;
  f32x4 c = *(const f32x4*)(Cd + (b << 9) + d);
  u16x4 o;
#pragma unroll
  for (int j = 0; j < 4; ++j) o[j] = f2b_u(x[j] - c[j]);
  *(u16x4*)(out + i) = o;
  if (blockIdx.x == 0 && threadIdx.x == 0) {
    outp[16777216] = Sh[0];
    outp[16777217] = Sc[0];
  }
}

// ---------- GEMM4 + fused GroupNorm ----------
__global__ __launch_bounds__(256) void gemm4_gn(
    const unsigned short* __restrict__ A, const unsigned short* __restrict__ B,
    const float* __restrict__ gnw, const float* __restrict__ gnb,
    float* __restrict__ out) {
  __shared__ __align__(16) unsigned short smem[18432];
  unsigned short(*sA)[72] = (unsigned short(*)[72])smem;
  unsigned short(*sB)[72] = (unsigned short(*)[72])(smem + 9216);

  const int blk = blockIdx.x;
  const int mt = blk & 255, n = blk >> 8;
  const int batch = mt >> 6;
  const int m0 = (mt & 63) << 7, n0 = n << 7;
  const unsigned short* A0 = A + (long)batch * 4194304;
  const unsigned short* B0 = B + (long)batch * 262144;
  const int tid = threadIdx.x;
  const int lane = tid & 63, wave = tid >> 6;
  const int wm = (wave & 1) << 6, wn = (wave >> 1) << 6;
  const int l16 = lane & 15, q8 = (lane >> 4) << 3;

  f32x4 acc[4][4] = {};

  for (int kt = 0; kt < 512; kt += 64) {
    u16x8 ra[4], rb[4];
#pragma unroll
    for (int i = 0; i < 4; ++i) {
      int c = tid + (i << 8);
      int row = c >> 3, col = (c & 7) << 3;
      ra[i] = *(const u16x8*)(A0 + (long)(m0 + row) * 512 + kt + col);
      rb[i] = *(const u16x8*)(B0 + (long)(n0 + row) * 512 + kt + col);
    }
    __syncthreads();
#pragma unroll
    for (int i = 0; i < 4; ++i) {
      int c = tid + (i << 8);
      int row = c >> 3, col = (c & 7) << 3;
      *(u16x8*)&sA[row][col] = ra[i];
      *(u16x8*)&sB[row][col] = rb[i];
    }
    __syncthreads();
#pragma unroll
    for (int kk = 0; kk < 2; ++kk) {
      bf16x8 af[4], bfv[4];
#pragma unroll
      for (int i = 0; i < 4; ++i) {
        af[i] = *(const bf16x8*)&sA[wm + (i << 4) + l16][(kk << 5) + q8];
        bfv[i] = *(const bf16x8*)&sB[wn + (i << 4) + l16][(kk << 5) + q8];
      }
#pragma unroll
      for (int i = 0; i < 4; ++i)
#pragma unroll
        for (int j = 0; j < 4; ++j)
          acc[i][j] = __builtin_amdgcn_mfma_f32_16x16x32_bf16(af[i], bfv[j], acc[i][j], 0, 0, 0);
    }
  }

  const int rq = (lane >> 4) << 2;
  float wv[4], bb[4];
#pragma unroll
  for (int j = 0; j < 4; ++j) {
    int gn = n0 + wn + (j << 4) + l16;
    wv[j] = gnw[gn];
    bb[j] = gnb[gn];
  }
  float* obase = out + (long)batch * 4194304;
#pragma unroll
  for (int i = 0; i < 4; ++i) {
    float mean[4], inv[4];
#pragma unroll
    for (int r = 0; r < 4; ++r) {
      float s = acc[i][0][r] + acc[i][1][r] + acc[i][2][r] + acc[i][3][r];
      s += __shfl_xor(s, 1);
      s += __shfl_xor(s, 2);
      s += __shfl_xor(s, 4);
      s += __shfl_xor(s, 8);
      mean[r] = s * (1.f / 64.f);
      float sq = 0.f;
#pragma unroll
      for (int j = 0; j < 4; ++j) {
        float d = acc[i][j][r] - mean[r];
        sq += d * d;
      }
      sq += __shfl_xor(sq, 1);
      sq += __shfl_xor(sq, 2);
      sq += __shfl_xor(sq, 4);
      sq += __shfl_xor(sq, 8);
      inv[r] = rsqrtf(sq * (1.f / 64.f) + 1e-6f);
    }
#pragma unroll
    for (int j = 0; j < 4; ++j) {
      int gn = n0 + wn + (j << 4) + l16;
#pragma unroll
      for (int r = 0; r < 4; ++r) {
        int gm = m0 + wm + (i << 4) + rq + r;
        obase[(long)gm * 512 + gn] = (acc[i][j][r] - mean[r]) * inv[r] * wv[j] + bb[j];
      }
    }
  }
}

// ---------- launch ----------
extern "C" void kernel_launch(void* const* d_in, const int* in_sizes, int n_in,
                              void* d_out, int out_size, void* d_ws, size_t ws_size,
                              hipStream_t stream) {
  const float* Xq = (const float*)d_in[0];
  const float* Xkv = (const float*)d_in[1];
  const float* Sh = (const float*)d_in[2];
  const float* Sc = (const float*)d_in[3];
  const float* Wq = (const float*)d_in[4];
  const float* bq = (const float*)d_in[5];
  // d_in[6]=Wk, d_in[7]=bk : dead code in reference
  const float* Wv = (const float*)d_in[8];
  const float* bv = (const float*)d_in[9];
  const float* gnw = (const float*)d_in[10];
  const float* gnb = (const float*)d_in[11];

  char* ws = (char*)d_ws;
  // layout (bytes), peak = 106,962,944 (proven available):
  unsigned short* QT = (unsigned short*)(ws);                // [4][512][8192] bf16
  unsigned short* VT = (unsigned short*)(ws + 33554432L);
  unsigned short* Kn = (unsigned short*)(ws + 67108864L);    // [4][8192][512] bf16
  float* C2f = (float*)(ws + 100663296L);                    // [4][512][512] f32 = 4 MB
  unsigned short* C2c = (unsigned short*)(ws + 104857600L);  // 2 MB
  float* Cd = (float*)(ws + 106954752L);                     // 8 KB
  // proj-phase overlays in the C2f region (dead until memset):
  unsigned short* Wqb = (unsigned short*)(ws + 100663296L);             // 0.5 MB
  unsigned short* Wvb = (unsigned short*)(ws + 100663296L + 524288L);   // 0.5 MB
  float* TBL = (float*)(ws + 100663296L + 1048576L);                    // 2 MB
  float* outp = (float*)d_out;

  if (ws_size < 106962944UL) return;

  // 0: weights fp32 -> bf16; rope table
  cvt_w<<<256, 256, 0, stream>>>(Wq, Wqb);
  cvt_w<<<256, 256, 0, stream>>>(Wv, Wvb);
  gen_tbl<<<1024, 256, 0, stream>>>(TBL);

  // 1+2: projections, full-N blocks (A fetched once)
  proj2<0><<<256, 1024, 0, stream>>>(Xq, Wqb, QT, bq, nullptr, TBL);
  proj2<1><<<256, 1024, 0, stream>>>(Xkv, Wvb, VT, bv, Kn, TBL);

  // 3: QtV^T accumulation (split-K=8, fp32 atomics)
  (void)hipMemsetAsync(C2f, 0, 4194304, stream);
  gemm_qtv<<<512, 256, 0, stream>>>(VT, QT, C2f);

  // 3b: center per (b,d), round to bf16; scalar passthrough
  colmean<<<2048, 64, 0, stream>>>(C2f, Cd);
  cvt_center<<<1024, 256, 0, stream>>>(C2f, Cd, C2c, Sh, Sc, outp);

  // 4: out = GroupNorm( K' @ (QtV - Cd) ) fused
  gemm4_gn<<<1024, 256, 0, stream>>>(Kn, C2c, gnw, gnb, outp);
}